// Round 5
// baseline (24071.617 us; speedup 1.0000x reference)
//
#include <hip/hip_runtime.h>

// SDGCN32: 31-layer GCN, N=100k, E=3.2M, F=32.
//  - hs = dis*h carried FP32 (fp16 carrier fails: 31-layer error amplification)
//  - edges sorted by (dst-block of NPB nodes, src-bucket of 32k nodes): 3128 groups
//  - k_layer: per block, LDS accumulator (stride 33); sweep 4 src-buckets in phase
//    (per-XCD L2 working set ~= one 3.2MB hs chunk); edge-parallel gather,
//    32 slots x unroll-4 = 128 edges in flight/block; ds_add_f32 accumulation
//    (fire-and-forget, no butterfly). Epilogue: *dis -> @W+b -> mynorm -> out accum.
//  - out accumulated online: out += mynorm(x_j)@Mn_j (+ raw x_j@Rw_j, j in {1,16})
//  - CSR fill: block-private LDS histogram + atomic range reservation + scatter

#define NPB 128     // nodes per dst-block (power of 2)
#define LB 7
#define NB 4        // src buckets
#define BSHIFT 15   // bucket = src >> 15 (32768 nodes = 4 MiB fp32 chunk)
#define GMAX 3200   // >= ceil(100000/128)*4 = 3128

__device__ __forceinline__ float shflx(float v, int m) { return __shfl_xor(v, m, 64); }

// ---------- degree histogram (for dis) ----------
__global__ void k_histd(const int* __restrict__ dst, int E, int* __restrict__ cnt) {
    int e = blockIdx.x * blockDim.x + threadIdx.x;
    if (e < E) atomicAdd(&cnt[dst[e]], 1);
}

__global__ void k_dis(const int* __restrict__ cnt, float* __restrict__ dis, int N) {
    int i = blockIdx.x * blockDim.x + threadIdx.x;
    if (i < N) dis[i] = rsqrtf((float)cnt[i] + 1.0f);
}

// ---------- group histogram: g = (dst>>LB)*NB + (src>>BSHIFT) ----------
__global__ __launch_bounds__(256) void k_hist_g(const int* __restrict__ src,
                                                const int* __restrict__ dst, int E,
                                                int* __restrict__ gcnt, int G) {
    __shared__ int lh[GMAX];
    for (int i = threadIdx.x; i < G; i += 256) lh[i] = 0;
    __syncthreads();
    int chunk = (E + gridDim.x - 1) / gridDim.x;
    int s0 = blockIdx.x * chunk, s1 = min(E, s0 + chunk);
    for (int e = s0 + threadIdx.x; e < s1; e += 256)
        atomicAdd(&lh[(dst[e] >> LB) * NB + (src[e] >> BSHIFT)], 1);
    __syncthreads();
    for (int i = threadIdx.x; i < G; i += 256)
        if (lh[i]) atomicAdd(&gcnt[i], lh[i]);
}

// ---------- scan over G<=4096 groups (single block) ----------
__global__ void k_scan_g(const int* __restrict__ gcnt, int* __restrict__ gptr,
                         int* __restrict__ gcur, int G, int E) {
    __shared__ int s[1024];
    int t = threadIdx.x;
    int loc[4]; int v = 0;
    int b0 = t * 4;
    for (int k = 0; k < 4; ++k) { int i = b0 + k; loc[k] = (i < G) ? gcnt[i] : 0; v += loc[k]; }
    s[t] = v;
    __syncthreads();
    for (int off = 1; off < 1024; off <<= 1) {
        int tv = (t >= off) ? s[t - off] : 0;
        __syncthreads();
        s[t] += tv;
        __syncthreads();
    }
    int run = s[t] - v;
    for (int k = 0; k < 4; ++k) {
        int i = b0 + k;
        if (i < G) { gptr[i] = run; gcur[i] = run; }
        run += loc[k];
    }
    if (t == 0) gptr[G] = E;
}

// ---------- fill: LDS hist -> reserve ranges -> scatter packed (src | ldst<<20) ----------
__global__ __launch_bounds__(256) void k_fill_g(const int* __restrict__ src,
                                                const int* __restrict__ dst, int E,
                                                int* __restrict__ gcur,
                                                int* __restrict__ csr, int G) {
    __shared__ int lh[GMAX];
    __shared__ int lc[GMAX];
    for (int i = threadIdx.x; i < G; i += 256) lh[i] = 0;
    __syncthreads();
    int chunk = (E + gridDim.x - 1) / gridDim.x;
    int s0 = blockIdx.x * chunk, s1 = min(E, s0 + chunk);
    for (int e = s0 + threadIdx.x; e < s1; e += 256)
        atomicAdd(&lh[(dst[e] >> LB) * NB + (src[e] >> BSHIFT)], 1);
    __syncthreads();
    for (int i = threadIdx.x; i < G; i += 256) {
        int c = lh[i];
        lc[i] = c ? atomicAdd(&gcur[i], c) : 0;
    }
    __syncthreads();
    for (int e = s0 + threadIdx.x; e < s1; e += 256) {
        int d = dst[e], sv = src[e];
        int g = (d >> LB) * NB + (sv >> BSHIFT);
        int pos = atomicAdd(&lc[g], 1);
        csr[pos] = sv | ((d & (NPB - 1)) << 20);
    }
}

// ---------- coefficients, layout [j][o][c] ----------
__global__ void k_mnorm(const float* __restrict__ W2, float* __restrict__ Mn,
                        float* __restrict__ Rw) {
    int idx = blockIdx.x * blockDim.x + threadIdx.x;
    if (idx >= 32 * 32 * 10) return;
    int c = idx % 32, o = (idx / 32) % 10, j = idx / 320;
    float v = 0.f;
    if (j >= 2 && j != 16) v += W2[(32 * j + c) * 10 + o];
    if (j <= 29 && j != 14) v -= W2[(32 * (j + 2) + c) * 10 + o];
    Mn[idx] = v;
    Rw[idx] = (j == 0 || j == 1 || j == 16) ? W2[(32 * j + c) * 10 + o] : 0.f;
}

// ---------- layer 0: x0 = mynorm(relu(x@W1+b1)); out init ----------
__global__ __launch_bounds__(256) void k_x0(
    const float* __restrict__ x, const float* __restrict__ W1, const float* __restrict__ b1,
    const float* __restrict__ W2, const float* __restrict__ b2, const float* __restrict__ M0,
    const float* __restrict__ dis, float* __restrict__ hs, float* __restrict__ out, int N)
{
    __shared__ float Ws[64 * 32];
    for (int i = threadIdx.x; i < 64 * 32; i += 256) Ws[i] = W1[i];
    __syncthreads();
    int wave = threadIdx.x >> 6;
    int lane = threadIdx.x & 63;
    int c = lane & 31, half = lane >> 5;
    int n = blockIdx.x * 4 + wave;
    if (n >= N) return;

    float xr = x[n * 64 + lane];
    float acc = 0.f;
#pragma unroll
    for (int kk = 0; kk < 32; ++kk) {
        float xv = __shfl(xr, half * 32 + kk, 64);
        acc += xv * Ws[(half * 32 + kk) * 32 + c];
    }
    acc += shflx(acc, 32);
    acc += b1[c];
    acc = fmaxf(acc, 0.f);
    float mn = acc, mx = acc;
#pragma unroll
    for (int m = 1; m <= 16; m <<= 1) { mn = fminf(mn, shflx(mn, m)); mx = fmaxf(mx, shflx(mx, m)); }
    float x0 = 2.f * (acc - mn) / (mx - mn + 1e-8f) - 1.f;
    float dn = dis[n];
    if (half == 0) hs[n * 32 + c] = dn * x0;
    mn = x0; mx = x0;
#pragma unroll
    for (int m = 1; m <= 16; m <<= 1) { mn = fminf(mn, shflx(mn, m)); mx = fmaxf(mx, shflx(mx, m)); }
    float n0 = 2.f * (x0 - mn) / (mx - mn + 1e-8f) - 1.f;
    float outv = 0.f;
#pragma unroll
    for (int o = 0; o < 10; ++o) {
        float t = x0 * W2[c * 10 + o] + n0 * M0[o * 32 + c];
#pragma unroll
        for (int m = 1; m <= 16; m <<= 1) t += shflx(t, m);
        if (lane == o) outv = t;
    }
    if (lane < 10) out[n * 10 + lane] = b2[lane] + outv;
}

// ---------- GCN layer j ----------
__global__ __launch_bounds__(256) void k_layer(
    const float4* __restrict__ hs_in, float4* __restrict__ hs_out,
    const float* __restrict__ dis, const int* __restrict__ gptr,
    const int* __restrict__ csr,
    const float* __restrict__ W, const float* __restrict__ b,
    const float* __restrict__ Mn, const float* __restrict__ Rw,
    float* __restrict__ out, int N, int israw)
{
    __shared__ float Ws[1024];      // W [k][c]
    __shared__ float bs[32];
    __shared__ float Ms[320];       // Mn_j [o][c]
    __shared__ float Rs[320];       // Rw_j [o][c]
    __shared__ float acc[NPB * 33]; // stride 33: atomics spread over banks

    int blk = blockIdx.x;
    int base = blk << LB;
    int cn = min(N - base, NPB);
    int tid = threadIdx.x;

    for (int i = tid; i < 1024; i += 256) Ws[i] = W[i];
    for (int i = tid; i < 320; i += 256) { Ms[i] = Mn[i]; Rs[i] = Rw[i]; }
    if (tid < 32) bs[tid] = b[tid];
    // init acc with self-loop term (coalesced read, strided LDS write: 2-way banks = free)
    {
        const float* hsf = (const float*)hs_in;
        for (int i = tid; i < cn * 32; i += 256)
            acc[(i >> 5) * 33 + (i & 31)] = hsf[(size_t)base * 32 + i];
    }
    __syncthreads();

    int q = tid & 7;        // channel quad c = 4q..4q+3
    int gs = tid >> 3;      // edge slot 0..31 (block-wide)
    for (int p = 0; p < NB; ++p) {
        int g = blk * NB + p;
        int st = gptr[g], en = gptr[g + 1];
        int e = st + gs;
        for (; e + 96 < en; e += 128) {            // 4 edges in flight per lane
            int w0 = csr[e], w1 = csr[e + 32], w2 = csr[e + 64], w3 = csr[e + 96];
            float4 v0 = hs_in[(size_t)(w0 & 0xFFFFF) * 8 + q];
            float4 v1 = hs_in[(size_t)(w1 & 0xFFFFF) * 8 + q];
            float4 v2 = hs_in[(size_t)(w2 & 0xFFFFF) * 8 + q];
            float4 v3 = hs_in[(size_t)(w3 & 0xFFFFF) * 8 + q];
            float* A0 = &acc[(w0 >> 20) * 33 + q * 4];
            float* A1 = &acc[(w1 >> 20) * 33 + q * 4];
            float* A2 = &acc[(w2 >> 20) * 33 + q * 4];
            float* A3 = &acc[(w3 >> 20) * 33 + q * 4];
            atomicAdd(A0 + 0, v0.x); atomicAdd(A0 + 1, v0.y); atomicAdd(A0 + 2, v0.z); atomicAdd(A0 + 3, v0.w);
            atomicAdd(A1 + 0, v1.x); atomicAdd(A1 + 1, v1.y); atomicAdd(A1 + 2, v1.z); atomicAdd(A1 + 3, v1.w);
            atomicAdd(A2 + 0, v2.x); atomicAdd(A2 + 1, v2.y); atomicAdd(A2 + 2, v2.z); atomicAdd(A2 + 3, v2.w);
            atomicAdd(A3 + 0, v3.x); atomicAdd(A3 + 1, v3.y); atomicAdd(A3 + 2, v3.z); atomicAdd(A3 + 3, v3.w);
        }
        for (; e < en; e += 32) {
            int w0 = csr[e];
            float4 v0 = hs_in[(size_t)(w0 & 0xFFFFF) * 8 + q];
            float* A0 = &acc[(w0 >> 20) * 33 + q * 4];
            atomicAdd(A0 + 0, v0.x); atomicAdd(A0 + 1, v0.y); atomicAdd(A0 + 2, v0.z); atomicAdd(A0 + 3, v0.w);
        }
        __syncthreads();    // bucket phase alignment
    }

    // epilogue per node
    int lane = tid & 63;
    int slot = lane >> 3;
    int wave = tid >> 6;
    for (int ni = wave; ni < cn; ni += 4) {
        int n = base + ni;
        float dn = dis[n];
        const float* A = &acc[ni * 33 + q * 4];
        float4 g4 = make_float4(dn * A[0], dn * A[1], dn * A[2], dn * A[3]);

        float gx = __shfl(g4.x, slot, 64);   // lane 'slot' has q==slot
        float gy = __shfl(g4.y, slot, 64);
        float gz = __shfl(g4.z, slot, 64);
        float gw = __shfl(g4.w, slot, 64);
        const float4* W4 = (const float4*)Ws;
        int k0 = slot * 4;
        float4 xn;
        {
            float4 w0 = W4[(k0 + 0) * 8 + q];
            float4 w1 = W4[(k0 + 1) * 8 + q];
            float4 w2 = W4[(k0 + 2) * 8 + q];
            float4 w3 = W4[(k0 + 3) * 8 + q];
            xn.x = gx * w0.x + gy * w1.x + gz * w2.x + gw * w3.x;
            xn.y = gx * w0.y + gy * w1.y + gz * w2.y + gw * w3.y;
            xn.z = gx * w0.z + gy * w1.z + gz * w2.z + gw * w3.z;
            xn.w = gx * w0.w + gy * w1.w + gz * w2.w + gw * w3.w;
        }
#pragma unroll
        for (int m = 8; m <= 32; m <<= 1) {
            xn.x += shflx(xn.x, m); xn.y += shflx(xn.y, m);
            xn.z += shflx(xn.z, m); xn.w += shflx(xn.w, m);
        }
        const float4* B4 = (const float4*)bs;
        float4 bb = B4[q];
        xn.x += bb.x; xn.y += bb.y; xn.z += bb.z; xn.w += bb.w;

        if (slot == 0)
            hs_out[(size_t)n * 8 + q] =
                make_float4(dn * xn.x, dn * xn.y, dn * xn.z, dn * xn.w);

        float mn = fminf(fminf(xn.x, xn.y), fminf(xn.z, xn.w));
        float mx = fmaxf(fmaxf(xn.x, xn.y), fmaxf(xn.z, xn.w));
#pragma unroll
        for (int m = 1; m <= 4; m <<= 1) { mn = fminf(mn, shflx(mn, m)); mx = fmaxf(mx, shflx(mx, m)); }
        float sc = 2.f / (mx - mn + 1e-8f);
        float4 nr = make_float4((xn.x - mn) * sc - 1.f, (xn.y - mn) * sc - 1.f,
                                (xn.z - mn) * sc - 1.f, (xn.w - mn) * sc - 1.f);

        const float4* M4 = (const float4*)Ms;
        const float4* R4 = (const float4*)Rs;
        float outv = 0.f;
#pragma unroll
        for (int o = 0; o < 10; ++o) {
            float4 m4 = M4[o * 8 + q];
            float t = nr.x * m4.x + nr.y * m4.y + nr.z * m4.z + nr.w * m4.w;
            if (israw) {
                float4 r4 = R4[o * 8 + q];
                t += xn.x * r4.x + xn.y * r4.y + xn.z * r4.z + xn.w * r4.w;
            }
            t += shflx(t, 1); t += shflx(t, 2); t += shflx(t, 4);
            if (lane == o) outv = t;
        }
        if (lane < 10) out[n * 10 + lane] += outv;
    }
}

extern "C" void kernel_launch(void* const* d_in, const int* in_sizes, int n_in,
                              void* d_out, int out_size, void* d_ws, size_t ws_size,
                              hipStream_t stream)
{
    const float* x  = (const float*)d_in[0];
    const int*   ei = (const int*)d_in[1];
    const float* W1 = (const float*)d_in[2];
    const float* b1 = (const float*)d_in[3];
    const float* Wc = (const float*)d_in[4];
    const float* bc = (const float*)d_in[5];
    const float* W2 = (const float*)d_in[6];
    const float* b2 = (const float*)d_in[7];
    float* out = (float*)d_out;

    const int N = in_sizes[0] / 64;
    const int E = in_sizes[1] / 2;
    const int NBLK = (N + NPB - 1) >> LB;     // 782
    const int G = NBLK * NB;                  // 3128 <= GMAX
    const int* src = ei;
    const int* dst = ei + E;

    char* ws = (char*)d_ws;
    size_t off = 0;
    auto alloc = [&](size_t bytes) -> void* {
        void* p = ws + off;
        off = (off + bytes + 255) & ~size_t(255);
        return p;
    };
    int*   cntd    = (int*)alloc((size_t)N * 4);
    int*   gcnt    = (int*)alloc((size_t)G * 4);
    int*   gptr    = (int*)alloc((size_t)(G + 1) * 4);
    int*   gcur    = (int*)alloc((size_t)G * 4);
    float* dis     = (float*)alloc((size_t)N * 4);
    int*   csr     = (int*)alloc((size_t)E * 4);
    float* hs_a    = (float*)alloc((size_t)N * 32 * 4);
    float* hs_b    = (float*)alloc((size_t)N * 32 * 4);
    float* Mn      = (float*)alloc(32 * 32 * 10 * 4);
    float* Rw      = (float*)alloc(32 * 32 * 10 * 4);

    hipMemsetAsync(cntd, 0, (size_t)N * 4, stream);
    hipMemsetAsync(gcnt, 0, (size_t)G * 4, stream);
    const int eb = (E + 255) / 256;
    const int nb = (N + 255) / 256;
    k_histd<<<eb, 256, 0, stream>>>(dst, E, cntd);
    k_dis<<<nb, 256, 0, stream>>>(cntd, dis, N);
    k_hist_g<<<256, 256, 0, stream>>>(src, dst, E, gcnt, G);
    k_scan_g<<<1, 1024, 0, stream>>>(gcnt, gptr, gcur, G, E);
    k_fill_g<<<256, 256, 0, stream>>>(src, dst, E, gcur, csr, G);
    k_mnorm<<<(32 * 32 * 10 + 255) / 256, 256, 0, stream>>>(W2, Mn, Rw);

    const int gb0 = (N + 3) / 4;
    k_x0<<<gb0, 256, 0, stream>>>(x, W1, b1, W2, b2, Mn, dis, hs_a, out, N);

    float* hin = hs_a; float* hout = hs_b;
    for (int j = 1; j <= 31; ++j) {
        int israw = (j == 1 || j == 16) ? 1 : 0;
        k_layer<<<NBLK, 256, 0, stream>>>((const float4*)hin, (float4*)hout, dis, gptr,
                                          csr,
                                          Wc + (size_t)(j - 1) * 1024,
                                          bc + (size_t)(j - 1) * 32,
                                          Mn + (size_t)j * 320,
                                          Rw + (size_t)j * 320,
                                          out, N, israw);
        float* t = hin; hin = hout; hout = t;
    }
}

// Round 6
// 7160.622 us; speedup vs baseline: 3.3617x; 3.3617x over previous
//
#include <hip/hip_runtime.h>

// SDGCN32: 31-layer GCN, N=100k, E=3.2M, F=32.
//  - hs = dis*h carried FP32 in GROUP-SPLIT layout [g][n][4ch], g = c>>2 (8 groups x 1.6MB)
//  - per layer, 2 kernels:
//      k_agg: block = (256-node slice, group g=blockIdx&7 -> XCD round-robin affinity);
//             lane-per-edge float4 gather from the 1.6MB group sub-array (L2-resident),
//             5-step half-wave butterfly (2 nodes/wave/iter), writes edge-sum agg[g][n].
//      k_upd: per node: g4 = dis*(agg+self) -> @W+b -> mynorm -> online out accum;
//             writes hs_out[g][n] in place over agg (same buffer, read-before-write per lane).
//  - out accumulated online: out += mynorm(x_j)@Mn_j (+ raw x_j@Rw_j, j in {1,16})
//  - CSR by dst built once (R2's histogram + scan + atomic-cursor fill)
//  - R4/R5 lessons: per-node bucket segments kill MLP; LDS atomics kill the DS pipe. Neither here.

#define SL 256      // nodes per slice in k_agg

__device__ __forceinline__ float shflx(float v, int m) { return __shfl_xor(v, m, 64); }

// ---------- CSR build ----------
__global__ void k_hist(const int* __restrict__ dst, int E, int* __restrict__ cnt) {
    int e = blockIdx.x * blockDim.x + threadIdx.x;
    if (e < E) atomicAdd(&cnt[dst[e]], 1);
}

__global__ void k_scan1(const int* __restrict__ cnt, int N, int* __restrict__ row_ptr,
                        int* __restrict__ bsums) {
    __shared__ int s[256];
    int i = blockIdx.x * 256 + threadIdx.x;
    int v = (i < N) ? cnt[i] : 0;
    s[threadIdx.x] = v;
    __syncthreads();
    for (int off = 1; off < 256; off <<= 1) {
        int t = (threadIdx.x >= off) ? s[threadIdx.x - off] : 0;
        __syncthreads();
        s[threadIdx.x] += t;
        __syncthreads();
    }
    int incl = s[threadIdx.x];
    if (i < N) row_ptr[i] = incl - v;
    if (threadIdx.x == 255) bsums[blockIdx.x] = incl;
}

__global__ void k_scan2(int* __restrict__ bsums, int nb) {
    __shared__ int s[512];
    int v = (threadIdx.x < nb) ? bsums[threadIdx.x] : 0;
    s[threadIdx.x] = v;
    __syncthreads();
    for (int off = 1; off < 512; off <<= 1) {
        int t = (threadIdx.x >= off) ? s[threadIdx.x - off] : 0;
        __syncthreads();
        s[threadIdx.x] += t;
        __syncthreads();
    }
    if (threadIdx.x < nb) bsums[threadIdx.x] = s[threadIdx.x] - v;
}

__global__ void k_scan3(int* __restrict__ row_ptr, const int* __restrict__ bsums,
                        const int* __restrict__ cnt, int N, int E,
                        int* __restrict__ cursor, float* __restrict__ dis) {
    int i = blockIdx.x * 256 + threadIdx.x;
    if (i < N) {
        int rp = row_ptr[i] + bsums[blockIdx.x];
        row_ptr[i] = rp;
        cursor[i] = rp;
        dis[i] = rsqrtf((float)cnt[i] + 1.0f);
    }
    if (i == 0) row_ptr[N] = E;
}

__global__ void k_fill(const int* __restrict__ src, const int* __restrict__ dst, int E,
                       int* __restrict__ cursor, int* __restrict__ csr_src) {
    int e = blockIdx.x * blockDim.x + threadIdx.x;
    if (e < E) {
        int pos = atomicAdd(&cursor[dst[e]], 1);
        csr_src[pos] = src[e];
    }
}

// ---------- coefficients, layout [j][o][c] ----------
__global__ void k_mnorm(const float* __restrict__ W2, float* __restrict__ Mn,
                        float* __restrict__ Rw) {
    int idx = blockIdx.x * blockDim.x + threadIdx.x;
    if (idx >= 32 * 32 * 10) return;
    int c = idx % 32, o = (idx / 32) % 10, j = idx / 320;
    float v = 0.f;
    if (j >= 2 && j != 16) v += W2[(32 * j + c) * 10 + o];
    if (j <= 29 && j != 14) v -= W2[(32 * (j + 2) + c) * 10 + o];
    Mn[idx] = v;
    Rw[idx] = (j == 0 || j == 1 || j == 16) ? W2[(32 * j + c) * 10 + o] : 0.f;
}

// ---------- layer 0: x0 = mynorm(relu(x@W1+b1)); out init; hs in group layout ----------
__global__ __launch_bounds__(256) void k_x0(
    const float* __restrict__ x, const float* __restrict__ W1, const float* __restrict__ b1,
    const float* __restrict__ W2, const float* __restrict__ b2, const float* __restrict__ M0,
    const float* __restrict__ dis, float* __restrict__ hs, float* __restrict__ out, int N)
{
    __shared__ float Ws[64 * 32];
    for (int i = threadIdx.x; i < 64 * 32; i += 256) Ws[i] = W1[i];
    __syncthreads();
    int wave = threadIdx.x >> 6;
    int lane = threadIdx.x & 63;
    int c = lane & 31, half = lane >> 5;
    int n = blockIdx.x * 4 + wave;
    if (n >= N) return;

    float xr = x[n * 64 + lane];
    float acc = 0.f;
#pragma unroll
    for (int kk = 0; kk < 32; ++kk) {
        float xv = __shfl(xr, half * 32 + kk, 64);
        acc += xv * Ws[(half * 32 + kk) * 32 + c];
    }
    acc += shflx(acc, 32);
    acc += b1[c];
    acc = fmaxf(acc, 0.f);
    float mn = acc, mx = acc;
#pragma unroll
    for (int m = 1; m <= 16; m <<= 1) { mn = fminf(mn, shflx(mn, m)); mx = fmaxf(mx, shflx(mx, m)); }
    float x0 = 2.f * (acc - mn) / (mx - mn + 1e-8f) - 1.f;
    float dn = dis[n];
    if (half == 0)
        hs[((size_t)(c >> 2) * N + n) * 4 + (c & 3)] = dn * x0;   // group-split layout
    mn = x0; mx = x0;
#pragma unroll
    for (int m = 1; m <= 16; m <<= 1) { mn = fminf(mn, shflx(mn, m)); mx = fmaxf(mx, shflx(mx, m)); }
    float n0 = 2.f * (x0 - mn) / (mx - mn + 1e-8f) - 1.f;
    float outv = 0.f;
#pragma unroll
    for (int o = 0; o < 10; ++o) {
        float t = x0 * W2[c * 10 + o] + n0 * M0[o * 32 + c];
#pragma unroll
        for (int m = 1; m <= 16; m <<= 1) t += shflx(t, m);
        if (lane == o) outv = t;
    }
    if (lane < 10) out[n * 10 + lane] = b2[lane] + outv;
}

// ---------- k_agg: edge-sum per (node, channel-group) ----------
__global__ __launch_bounds__(256) void k_agg(
    const float4* __restrict__ hs_in, float4* __restrict__ agg,
    const int* __restrict__ row_ptr, const int* __restrict__ csr_src, int N)
{
    int g = blockIdx.x & 7;                  // XCD round-robin affinity
    int base = (blockIdx.x >> 3) * SL;
    const float4* __restrict__ hsg = hs_in + (size_t)g * N;
    float4* __restrict__ ag = agg + (size_t)g * N;

    int lane = threadIdx.x & 63;
    int wave = threadIdx.x >> 6;
    int half = lane >> 5;                    // which of 2 nodes
    int l5 = lane & 31;                      // edge slot within node

    for (int ni = wave * 2 + half; ni < SL; ni += 8) {
        int n = base + ni;
        if (n >= N) break;
        int rs = row_ptr[n], re = row_ptr[n + 1];
        float4 a = make_float4(0.f, 0.f, 0.f, 0.f);
        for (int e = rs + l5; e < re; e += 32) {
            int s = csr_src[e];
            float4 v = hsg[s];
            a.x += v.x; a.y += v.y; a.z += v.z; a.w += v.w;
        }
#pragma unroll
        for (int m = 1; m <= 16; m <<= 1) {  // reduce within 32-lane half
            a.x += shflx(a.x, m); a.y += shflx(a.y, m);
            a.z += shflx(a.z, m); a.w += shflx(a.w, m);
        }
        if (l5 == 0) ag[n] = a;
    }
}

// ---------- k_upd: g=dis*(agg+self) -> @W+b -> mynorm -> out; hs_out over agg ----------
__global__ __launch_bounds__(256) void k_upd(
    const float4* __restrict__ hs_in, float4* __restrict__ agg_hsout,
    const float* __restrict__ dis,
    const float* __restrict__ W, const float* __restrict__ b,
    const float* __restrict__ Mn, const float* __restrict__ Rw,
    float* __restrict__ out, int N, int israw)
{
    __shared__ float Ws[1024];   // W [k][c]
    __shared__ float bs[32];
    __shared__ float Ms[320];    // Mn_j [o][c]
    __shared__ float Rs[320];    // Rw_j [o][c]
    for (int i = threadIdx.x; i < 1024; i += 256) Ws[i] = W[i];
    for (int i = threadIdx.x; i < 320; i += 256) { Ms[i] = Mn[i]; Rs[i] = Rw[i]; }
    if (threadIdx.x < 32) bs[threadIdx.x] = b[threadIdx.x];
    __syncthreads();

    int lane = threadIdx.x & 63;
    int q = lane & 7;            // channel quad c = 4q..4q+3
    int slot = lane >> 3;
    int wave = threadIdx.x >> 6;

    for (int ni = 0; ni < 4; ++ni) {
        int n = blockIdx.x * 16 + wave * 4 + ni;
        if (n >= N) return;
        float dn = dis[n];
        float4 a4 = agg_hsout[(size_t)q * N + n];   // all slots same addr -> broadcast
        float4 s4 = hs_in[(size_t)q * N + n];       // self-loop term
        float4 g4 = make_float4(dn * (a4.x + s4.x), dn * (a4.y + s4.y),
                                dn * (a4.z + s4.z), dn * (a4.w + s4.w));

        float gx = __shfl(g4.x, slot, 64);   // lane 'slot' has q==slot, slot==0
        float gy = __shfl(g4.y, slot, 64);
        float gz = __shfl(g4.z, slot, 64);
        float gw = __shfl(g4.w, slot, 64);
        const float4* W4 = (const float4*)Ws;
        int k0 = slot * 4;
        float4 xn;
        {
            float4 w0 = W4[(k0 + 0) * 8 + q];
            float4 w1 = W4[(k0 + 1) * 8 + q];
            float4 w2 = W4[(k0 + 2) * 8 + q];
            float4 w3 = W4[(k0 + 3) * 8 + q];
            xn.x = gx * w0.x + gy * w1.x + gz * w2.x + gw * w3.x;
            xn.y = gx * w0.y + gy * w1.y + gz * w2.y + gw * w3.y;
            xn.z = gx * w0.z + gy * w1.z + gz * w2.z + gw * w3.z;
            xn.w = gx * w0.w + gy * w1.w + gz * w2.w + gw * w3.w;
        }
#pragma unroll
        for (int m = 8; m <= 32; m <<= 1) {
            xn.x += shflx(xn.x, m); xn.y += shflx(xn.y, m);
            xn.z += shflx(xn.z, m); xn.w += shflx(xn.w, m);
        }
        const float4* B4 = (const float4*)bs;
        float4 bb = B4[q];
        xn.x += bb.x; xn.y += bb.y; xn.z += bb.z; xn.w += bb.w;

        if (slot == 0)
            agg_hsout[(size_t)q * N + n] =
                make_float4(dn * xn.x, dn * xn.y, dn * xn.z, dn * xn.w);

        float mn = fminf(fminf(xn.x, xn.y), fminf(xn.z, xn.w));
        float mx = fmaxf(fmaxf(xn.x, xn.y), fmaxf(xn.z, xn.w));
#pragma unroll
        for (int m = 1; m <= 4; m <<= 1) { mn = fminf(mn, shflx(mn, m)); mx = fmaxf(mx, shflx(mx, m)); }
        float sc = 2.f / (mx - mn + 1e-8f);
        float4 nr = make_float4((xn.x - mn) * sc - 1.f, (xn.y - mn) * sc - 1.f,
                                (xn.z - mn) * sc - 1.f, (xn.w - mn) * sc - 1.f);

        const float4* M4 = (const float4*)Ms;
        const float4* R4 = (const float4*)Rs;
        float outv = 0.f;
#pragma unroll
        for (int o = 0; o < 10; ++o) {
            float4 m4 = M4[o * 8 + q];
            float t = nr.x * m4.x + nr.y * m4.y + nr.z * m4.z + nr.w * m4.w;
            if (israw) {
                float4 r4 = R4[o * 8 + q];
                t += xn.x * r4.x + xn.y * r4.y + xn.z * r4.z + xn.w * r4.w;
            }
            t += shflx(t, 1); t += shflx(t, 2); t += shflx(t, 4);
            if (lane == o) outv = t;
        }
        if (lane < 10) out[n * 10 + lane] += outv;
    }
}

extern "C" void kernel_launch(void* const* d_in, const int* in_sizes, int n_in,
                              void* d_out, int out_size, void* d_ws, size_t ws_size,
                              hipStream_t stream)
{
    const float* x  = (const float*)d_in[0];
    const int*   ei = (const int*)d_in[1];
    const float* W1 = (const float*)d_in[2];
    const float* b1 = (const float*)d_in[3];
    const float* Wc = (const float*)d_in[4];
    const float* bc = (const float*)d_in[5];
    const float* W2 = (const float*)d_in[6];
    const float* b2 = (const float*)d_in[7];
    float* out = (float*)d_out;

    const int N = in_sizes[0] / 64;
    const int E = in_sizes[1] / 2;
    const int* src = ei;
    const int* dst = ei + E;

    char* ws = (char*)d_ws;
    size_t off = 0;
    auto alloc = [&](size_t bytes) -> void* {
        void* p = ws + off;
        off = (off + bytes + 255) & ~size_t(255);
        return p;
    };
    int*   cnt     = (int*)alloc((size_t)N * 4);
    int*   row_ptr = (int*)alloc((size_t)(N + 1) * 4);
    int*   cursor  = (int*)alloc((size_t)N * 4);
    int*   bsums   = (int*)alloc(512 * 4);
    float* dis     = (float*)alloc((size_t)N * 4);
    int*   csr_src = (int*)alloc((size_t)E * 4);
    float* hs_a    = (float*)alloc((size_t)N * 32 * 4);
    float* hs_b    = (float*)alloc((size_t)N * 32 * 4);
    float* Mn      = (float*)alloc(32 * 32 * 10 * 4);
    float* Rw      = (float*)alloc(32 * 32 * 10 * 4);

    hipMemsetAsync(cnt, 0, (size_t)N * 4, stream);
    const int eb = (E + 255) / 256;
    const int nb = (N + 255) / 256;          // 391 <= 512 for scan2
    k_hist<<<eb, 256, 0, stream>>>(dst, E, cnt);
    k_scan1<<<nb, 256, 0, stream>>>(cnt, N, row_ptr, bsums);
    k_scan2<<<1, 512, 0, stream>>>(bsums, nb);
    k_scan3<<<nb, 256, 0, stream>>>(row_ptr, bsums, cnt, N, E, cursor, dis);
    k_fill<<<eb, 256, 0, stream>>>(src, dst, E, cursor, csr_src);
    k_mnorm<<<(32 * 32 * 10 + 255) / 256, 256, 0, stream>>>(W2, Mn, Rw);

    const int gb0 = (N + 3) / 4;
    k_x0<<<gb0, 256, 0, stream>>>(x, W1, b1, W2, b2, Mn, dis, hs_a, out, N);

    const int nslice = (N + SL - 1) / SL;    // 391
    const int gbA = nslice * 8;              // 3128 blocks: (slice, group)
    const int gbB = (N + 15) / 16;           // 6250 blocks, 16 nodes each

    float* hin = hs_a; float* hout = hs_b;
    for (int j = 1; j <= 31; ++j) {
        int israw = (j == 1 || j == 16) ? 1 : 0;
        k_agg<<<gbA, 256, 0, stream>>>((const float4*)hin, (float4*)hout,
                                       row_ptr, csr_src, N);
        k_upd<<<gbB, 256, 0, stream>>>((const float4*)hin, (float4*)hout, dis,
                                       Wc + (size_t)(j - 1) * 1024,
                                       bc + (size_t)(j - 1) * 32,
                                       Mn + (size_t)j * 320,
                                       Rw + (size_t)j * 320,
                                       out, N, israw);
        float* t = hin; hin = hout; hout = t;
    }
}

// Round 7
// 2426.644 us; speedup vs baseline: 9.9197x; 2.9508x over previous
//
#include <hip/hip_runtime.h>

// SDGCN32: 31-layer GCN, N=100k, E=3.2M, F=32.
//  - hs = dis*h carried FP32, row-major [n][32] (128B rows; fp16 carrier fails 31-layer error amp)
//  - CSR per (dst, src-bucket): 4 buckets of 32k nodes (4MiB hs chunks)
//  - k_gcn: wave = 8 nodes x 8 quads. Lanes (i,0..7) walk node i's segment in lockstep
//    -> one 128B line per edge (coalesced, R6 lesson). Register accumulation across all
//    4 buckets (no butterflies/LDS atomics, R4/R5 lessons), unroll-4 -> 32 loads in flight.
//    Buckets swept in phase (__syncthreads) -> per-XCD L2 working set ~= one 4MiB chunk.
//    Epilogue 8-nodes-parallel: dynamic-shfl GEMM + q-bit butterflies for mynorm/out.
//  - out accumulated online: out += mynorm(x_j)@Mn_j (+ raw x_j@Rw_j, j in {1,16})

#define NB 4        // src buckets
#define BSHIFT 15   // bucket = src >> 15 (32768 nodes = 4 MiB fp32 chunk)

__device__ __forceinline__ float shflx(float v, int m) { return __shfl_xor(v, m, 64); }

// ---------- CSR build (per-(dst,bucket) segments) ----------
__global__ void k_hist(const int* __restrict__ src, const int* __restrict__ dst, int E,
                       int* __restrict__ cnt) {
    int e = blockIdx.x * blockDim.x + threadIdx.x;
    if (e < E) atomicAdd(&cnt[dst[e] * NB + (src[e] >> BSHIFT)], 1);
}

__global__ void k_scan1(const int* __restrict__ cnt, int M, int* __restrict__ row_ptr,
                        int* __restrict__ bsums) {
    __shared__ int s[512];
    int i = blockIdx.x * 512 + threadIdx.x;
    int v = (i < M) ? cnt[i] : 0;
    s[threadIdx.x] = v;
    __syncthreads();
    for (int off = 1; off < 512; off <<= 1) {
        int t = (threadIdx.x >= off) ? s[threadIdx.x - off] : 0;
        __syncthreads();
        s[threadIdx.x] += t;
        __syncthreads();
    }
    int incl = s[threadIdx.x];
    if (i < M) row_ptr[i] = incl - v;
    if (threadIdx.x == 511) bsums[blockIdx.x] = incl;
}

__global__ void k_scan2(int* __restrict__ bsums, int nb) {
    __shared__ int s[1024];
    int v = (threadIdx.x < nb) ? bsums[threadIdx.x] : 0;
    s[threadIdx.x] = v;
    __syncthreads();
    for (int off = 1; off < 1024; off <<= 1) {
        int t = (threadIdx.x >= off) ? s[threadIdx.x - off] : 0;
        __syncthreads();
        s[threadIdx.x] += t;
        __syncthreads();
    }
    if (threadIdx.x < nb) bsums[threadIdx.x] = s[threadIdx.x] - v;
}

__global__ void k_scan3(int* __restrict__ row_ptr, const int* __restrict__ bsums,
                        const int* __restrict__ cnt, int M, int E,
                        int* __restrict__ cursor, float* __restrict__ dis) {
    int i = blockIdx.x * 512 + threadIdx.x;
    if (i < M) {
        int rp = row_ptr[i] + bsums[blockIdx.x];
        row_ptr[i] = rp;
        cursor[i] = rp;
        if ((i & (NB - 1)) == 0) {
            float deg = (float)(cnt[i] + cnt[i + 1] + cnt[i + 2] + cnt[i + 3]);
            dis[i / NB] = rsqrtf(deg + 1.0f);
        }
    }
    if (i == 0) row_ptr[M] = E;
}

__global__ void k_fill(const int* __restrict__ src, const int* __restrict__ dst, int E,
                       int* __restrict__ cursor, int* __restrict__ csr_src) {
    int e = blockIdx.x * blockDim.x + threadIdx.x;
    if (e < E) {
        int s = src[e];
        int pos = atomicAdd(&cursor[dst[e] * NB + (s >> BSHIFT)], 1);
        csr_src[pos] = s;
    }
}

// ---------- coefficients, layout [j][o][c] ----------
__global__ void k_mnorm(const float* __restrict__ W2, float* __restrict__ Mn,
                        float* __restrict__ Rw) {
    int idx = blockIdx.x * blockDim.x + threadIdx.x;
    if (idx >= 32 * 32 * 10) return;
    int c = idx % 32, o = (idx / 32) % 10, j = idx / 320;
    float v = 0.f;
    if (j >= 2 && j != 16) v += W2[(32 * j + c) * 10 + o];
    if (j <= 29 && j != 14) v -= W2[(32 * (j + 2) + c) * 10 + o];
    Mn[idx] = v;
    Rw[idx] = (j == 0 || j == 1 || j == 16) ? W2[(32 * j + c) * 10 + o] : 0.f;
}

// ---------- layer 0: x0 = mynorm(relu(x@W1+b1)); out init; hs row-major ----------
__global__ __launch_bounds__(256) void k_x0(
    const float* __restrict__ x, const float* __restrict__ W1, const float* __restrict__ b1,
    const float* __restrict__ W2, const float* __restrict__ b2, const float* __restrict__ M0,
    const float* __restrict__ dis, float* __restrict__ hs, float* __restrict__ out, int N)
{
    __shared__ float Ws[64 * 32];
    for (int i = threadIdx.x; i < 64 * 32; i += 256) Ws[i] = W1[i];
    __syncthreads();
    int wave = threadIdx.x >> 6;
    int lane = threadIdx.x & 63;
    int c = lane & 31, half = lane >> 5;
    int n = blockIdx.x * 4 + wave;
    if (n >= N) return;

    float xr = x[n * 64 + lane];
    float acc = 0.f;
#pragma unroll
    for (int kk = 0; kk < 32; ++kk) {
        float xv = __shfl(xr, half * 32 + kk, 64);
        acc += xv * Ws[(half * 32 + kk) * 32 + c];
    }
    acc += shflx(acc, 32);
    acc += b1[c];
    acc = fmaxf(acc, 0.f);
    float mn = acc, mx = acc;
#pragma unroll
    for (int m = 1; m <= 16; m <<= 1) { mn = fminf(mn, shflx(mn, m)); mx = fmaxf(mx, shflx(mx, m)); }
    float x0 = 2.f * (acc - mn) / (mx - mn + 1e-8f) - 1.f;
    float dn = dis[n];
    if (half == 0) hs[n * 32 + c] = dn * x0;
    mn = x0; mx = x0;
#pragma unroll
    for (int m = 1; m <= 16; m <<= 1) { mn = fminf(mn, shflx(mn, m)); mx = fmaxf(mx, shflx(mx, m)); }
    float n0 = 2.f * (x0 - mn) / (mx - mn + 1e-8f) - 1.f;
    float outv = 0.f;
#pragma unroll
    for (int o = 0; o < 10; ++o) {
        float t = x0 * W2[c * 10 + o] + n0 * M0[o * 32 + c];
#pragma unroll
        for (int m = 1; m <= 16; m <<= 1) t += shflx(t, m);
        if (lane == o) outv = t;
    }
    if (lane < 10) out[n * 10 + lane] = b2[lane] + outv;
}

// ---------- GCN layer: register-acc bucketed gather + parallel epilogue ----------
__global__ __launch_bounds__(256) void k_gcn(
    const float4* __restrict__ hs_in, float4* __restrict__ hs_out,
    const float* __restrict__ dis, const int* __restrict__ rp4,
    const int* __restrict__ csr,
    const float* __restrict__ W, const float* __restrict__ b,
    const float* __restrict__ Mn, const float* __restrict__ Rw,
    float* __restrict__ out, int N, int israw)
{
    __shared__ float Ws[1024];   // W [k][c]
    __shared__ float bs[32];
    __shared__ float Ms[320];    // Mn_j [o][c]
    __shared__ float Rs[320];    // Rw_j [o][c]
    for (int i = threadIdx.x; i < 1024; i += 256) Ws[i] = W[i];
    for (int i = threadIdx.x; i < 320; i += 256) { Ms[i] = Mn[i]; Rs[i] = Rw[i]; }
    if (threadIdx.x < 32) bs[threadIdx.x] = b[threadIdx.x];
    __syncthreads();

    int lane = threadIdx.x & 63;
    int q = lane & 7;            // channel quad c = 4q..4q+3
    int i8 = lane >> 3;          // node-sub 0..7
    int wave = threadIdx.x >> 6;
    int n = blockIdx.x * 32 + wave * 8 + i8;
    bool valid = (n < N);
    int nn = valid ? n : (N - 1);       // clamp: extra harmless loads only

    // self-loop term; lanes (i,0..7) -> 8 consecutive 128B rows = 1KB coalesced
    float4 acc = hs_in[(size_t)nn * 8 + q];

    int rbase = nn * NB;
    for (int p = 0; p < NB; ++p) {
        int rs = rp4[rbase + p], re = rp4[rbase + p + 1];
        int e = rs;
        for (; e + 3 < re; e += 4) {
            int s0 = csr[e], s1 = csr[e + 1], s2 = csr[e + 2], s3 = csr[e + 3];
            float4 v0 = hs_in[(size_t)s0 * 8 + q];
            float4 v1 = hs_in[(size_t)s1 * 8 + q];
            float4 v2 = hs_in[(size_t)s2 * 8 + q];
            float4 v3 = hs_in[(size_t)s3 * 8 + q];
            acc.x += v0.x; acc.y += v0.y; acc.z += v0.z; acc.w += v0.w;
            acc.x += v1.x; acc.y += v1.y; acc.z += v1.z; acc.w += v1.w;
            acc.x += v2.x; acc.y += v2.y; acc.z += v2.z; acc.w += v2.w;
            acc.x += v3.x; acc.y += v3.y; acc.z += v3.z; acc.w += v3.w;
        }
        if (e + 1 < re) {
            int s0 = csr[e], s1 = csr[e + 1];
            float4 v0 = hs_in[(size_t)s0 * 8 + q];
            float4 v1 = hs_in[(size_t)s1 * 8 + q];
            acc.x += v0.x; acc.y += v0.y; acc.z += v0.z; acc.w += v0.w;
            acc.x += v1.x; acc.y += v1.y; acc.z += v1.z; acc.w += v1.w;
            e += 2;
        }
        if (e < re) {
            int s0 = csr[e];
            float4 v0 = hs_in[(size_t)s0 * 8 + q];
            acc.x += v0.x; acc.y += v0.y; acc.z += v0.z; acc.w += v0.w;
        }
        __syncthreads();         // bucket phase alignment (uniform: all threads loop NB times)
    }

    float dn = dis[nn];
    float4 g = make_float4(dn * acc.x, dn * acc.y, dn * acc.z, dn * acc.w);

    // GEMM: xn[quad q of node i] = b + sum_k g_i[k] * W[k][4q..4q+3]
    const float4* W4 = (const float4*)Ws;
    float4 bb = ((const float4*)bs)[q];
    float4 xn = bb;
    int ibase = lane & 0x38;     // i8<<3
#pragma unroll
    for (int kp = 0; kp < 8; ++kp) {
        int sl = ibase | kp;     // lane holding quad kp of node i
        float gx = __shfl(g.x, sl, 64);
        float gy = __shfl(g.y, sl, 64);
        float gz = __shfl(g.z, sl, 64);
        float gw = __shfl(g.w, sl, 64);
        float4 w0 = W4[(kp * 4 + 0) * 8 + q];
        float4 w1 = W4[(kp * 4 + 1) * 8 + q];
        float4 w2 = W4[(kp * 4 + 2) * 8 + q];
        float4 w3 = W4[(kp * 4 + 3) * 8 + q];
        xn.x += gx * w0.x + gy * w1.x + gz * w2.x + gw * w3.x;
        xn.y += gx * w0.y + gy * w1.y + gz * w2.y + gw * w3.y;
        xn.z += gx * w0.z + gy * w1.z + gz * w2.z + gw * w3.z;
        xn.w += gx * w0.w + gy * w1.w + gz * w2.w + gw * w3.w;
    }

    if (valid)
        hs_out[(size_t)n * 8 + q] = make_float4(dn * xn.x, dn * xn.y, dn * xn.z, dn * xn.w);

    // mynorm over node's 32 channels: local 4, then butterfly over q bits (1,2,4)
    float mn = fminf(fminf(xn.x, xn.y), fminf(xn.z, xn.w));
    float mx = fmaxf(fmaxf(xn.x, xn.y), fmaxf(xn.z, xn.w));
#pragma unroll
    for (int m = 1; m <= 4; m <<= 1) { mn = fminf(mn, shflx(mn, m)); mx = fmaxf(mx, shflx(mx, m)); }
    float sc = 2.f / (mx - mn + 1e-8f);
    float4 nr = make_float4((xn.x - mn) * sc - 1.f, (xn.y - mn) * sc - 1.f,
                            (xn.z - mn) * sc - 1.f, (xn.w - mn) * sc - 1.f);

    // out accum: t[o] = nr . Mn[o][:] (+ xn . Rw[o][:]); butterfly within q bits
    const float4* M4 = (const float4*)Ms;
    const float4* R4 = (const float4*)Rs;
    float outA = 0.f, outB = 0.f;
#pragma unroll
    for (int o = 0; o < 10; ++o) {
        float4 m4 = M4[o * 8 + q];
        float t = nr.x * m4.x + nr.y * m4.y + nr.z * m4.z + nr.w * m4.w;
        if (israw) {
            float4 r4 = R4[o * 8 + q];
            t += xn.x * r4.x + xn.y * r4.y + xn.z * r4.z + xn.w * r4.w;
        }
        t += shflx(t, 1); t += shflx(t, 2); t += shflx(t, 4);
        if (o == q) outA = t;
        if (o == 8 + q) outB = t;
    }
    if (valid) {
        out[n * 10 + q] += outA;
        if (q < 2) out[n * 10 + 8 + q] += outB;
    }
}

extern "C" void kernel_launch(void* const* d_in, const int* in_sizes, int n_in,
                              void* d_out, int out_size, void* d_ws, size_t ws_size,
                              hipStream_t stream)
{
    const float* x  = (const float*)d_in[0];
    const int*   ei = (const int*)d_in[1];
    const float* W1 = (const float*)d_in[2];
    const float* b1 = (const float*)d_in[3];
    const float* Wc = (const float*)d_in[4];
    const float* bc = (const float*)d_in[5];
    const float* W2 = (const float*)d_in[6];
    const float* b2 = (const float*)d_in[7];
    float* out = (float*)d_out;

    const int N = in_sizes[0] / 64;
    const int E = in_sizes[1] / 2;
    const int M = N * NB;                     // (node,bucket) rows
    const int* src = ei;
    const int* dst = ei + E;

    char* ws = (char*)d_ws;
    size_t off = 0;
    auto alloc = [&](size_t bytes) -> void* {
        void* p = ws + off;
        off = (off + bytes + 255) & ~size_t(255);
        return p;
    };
    int*   cnt     = (int*)alloc((size_t)M * 4);
    int*   rp4     = (int*)alloc((size_t)(M + 1) * 4);
    int*   cursor  = (int*)alloc((size_t)M * 4);
    int*   bsums   = (int*)alloc(1024 * 4);
    float* dis     = (float*)alloc((size_t)N * 4);
    int*   csr     = (int*)alloc((size_t)E * 4);
    float* hs_a    = (float*)alloc((size_t)N * 32 * 4);
    float* hs_b    = (float*)alloc((size_t)N * 32 * 4);
    float* Mn      = (float*)alloc(32 * 32 * 10 * 4);
    float* Rw      = (float*)alloc(32 * 32 * 10 * 4);

    hipMemsetAsync(cnt, 0, (size_t)M * 4, stream);
    const int eb = (E + 255) / 256;
    const int sb = (M + 511) / 512;           // 782 <= 1024 for scan2
    k_hist<<<eb, 256, 0, stream>>>(src, dst, E, cnt);
    k_scan1<<<sb, 512, 0, stream>>>(cnt, M, rp4, bsums);
    k_scan2<<<1, 1024, 0, stream>>>(bsums, sb);
    k_scan3<<<sb, 512, 0, stream>>>(rp4, bsums, cnt, M, E, cursor, dis);
    k_fill<<<eb, 256, 0, stream>>>(src, dst, E, cursor, csr);
    k_mnorm<<<(32 * 32 * 10 + 255) / 256, 256, 0, stream>>>(W2, Mn, Rw);

    const int gb0 = (N + 3) / 4;
    k_x0<<<gb0, 256, 0, stream>>>(x, W1, b1, W2, b2, Mn, dis, hs_a, out, N);

    const int gb = (N + 31) / 32;             // 3125 blocks, 32 nodes each
    float* hin = hs_a; float* hout = hs_b;
    for (int j = 1; j <= 31; ++j) {
        int israw = (j == 1 || j == 16) ? 1 : 0;
        k_gcn<<<gb, 256, 0, stream>>>((const float4*)hin, (float4*)hout, dis, rp4,
                                      csr,
                                      Wc + (size_t)(j - 1) * 1024,
                                      bc + (size_t)(j - 1) * 32,
                                      Mn + (size_t)j * 320,
                                      Rw + (size_t)j * 320,
                                      out, N, israw);
        float* t = hin; hin = hout; hout = t;
    }
}